// Round 4
// baseline (320.199 us; speedup 1.0000x reference)
//
#include <hip/hip_runtime.h>
#include <math.h>

#define L 512
#define NCH 21      // channels in x
#define H 30        // seq_hmm rows
#define NAA 20      // aa channels used (x[:,1:,:])
#define WSTRIDE 50  // W is [3, 20+H] = [3, 50]

typedef float v4f __attribute__((ext_vector_type(4)));

// proj[o*L + l] = sum_h W[o][20+h] * seq_hmm[h][l] + b[o]
// One-time precompute (R1-proven: cheaper than per-block recompute, R4 -6us).
__global__ void precompute_proj(const float* __restrict__ seq_hmm,
                                const float* __restrict__ W,
                                const float* __restrict__ bvec,
                                float* __restrict__ proj) {
    const int l = threadIdx.x;  // 512 threads, 1 block
    float a0 = bvec[0], a1 = bvec[1], a2 = bvec[2];
#pragma unroll
    for (int h = 0; h < H; ++h) {
        const float s = seq_hmm[h * L + l];
        a0 = fmaf(W[0 * WSTRIDE + NAA + h], s, a0);
        a1 = fmaf(W[1 * WSTRIDE + NAA + h], s, a1);
        a2 = fmaf(W[2 * WSTRIDE + NAA + h], s, a2);
    }
    proj[0 * L + l] = a0;
    proj[1 * L + l] = a1;
    proj[2 * L + l] = a2;
}

// R8: one wave per sample; SPLIT-CONTIGUOUS 8 cols/lane: lane t owns cols
// [4t,4t+4) and [256+4t,256+4t+4). Each dwordx4 wave-instruction covers a
// contiguous 1KB half-row (full cache-line payload) -- R3's l0=8t layout
// made stride-32B half-payload requests (why it was null vs R0).
// 40 full-width requests/wave/sample, 2x R0's depth. In-loop live state
// slimmed to a[24]+m[8] (xg/proj/ss loaded AFTER the loop; L2-hot);
// __launch_bounds__(64,4) caps VGPR at 128 -> 16 waves/CU with ~85 regs
// for load buffers. Per-CU in-flight target ~640KB (R0/R3 were ~320KB ->
// 4.2-4.4 TB/s; R1 clamp ~32KB -> 3.2 TB/s).
// R5 POST-MORTEM: never clamp below ILP needs (256,8 -> VGPR32 disaster).
// NOTE: precise expf/logf required -- __expf/__logf fail absmax (R2: 2.7e-2).
// NOTE: plain cached loads -- nontemporal bypassed L3, +4-10us (R3/R4).
__global__ __launch_bounds__(64, 4) void qpml_main(
        const float* __restrict__ x,       // [B,21,L]
        const float* __restrict__ ss_hmm,  // [3,L]
        const float* __restrict__ W,       // [3,50]
        const float* __restrict__ proj,    // [3,L]
        float* __restrict__ out) {         // [B]
    const int b = blockIdx.x;
    const int t = threadIdx.x;  // 0..63
    const float* xb = x + (size_t)b * NCH * L;
    const int lA = 4 * t;        // first 4-col group
    const int lB = 256 + 4 * t;  // second 4-col group (other half-row)

    // Stream x channels 1..20 with minimal live state: a[3][8] + m[8].
    float a[3][8], m[8];
#pragma unroll
    for (int j = 0; j < 8; ++j) m[j] = -INFINITY;
#pragma unroll
    for (int o = 0; o < 3; ++o)
#pragma unroll
        for (int j = 0; j < 8; ++j) a[o][j] = 0.0f;

#pragma unroll
    for (int c = 1; c < NCH; ++c) {
        const v4f v0 = *(const v4f*)(xb + c * L + lA);
        const v4f v1 = *(const v4f*)(xb + c * L + lB);
        // uniform addresses -> scalar loads, hoisted by compiler
        const float w0 = W[0 * WSTRIDE + (c - 1)];
        const float w1 = W[1 * WSTRIDE + (c - 1)];
        const float w2 = W[2 * WSTRIDE + (c - 1)];
#pragma unroll
        for (int j = 0; j < 4; ++j) {
            m[j] = fmaxf(m[j], v0[j]);
            a[0][j] = fmaf(w0, v0[j], a[0][j]);
            a[1][j] = fmaf(w1, v0[j], a[1][j]);
            a[2][j] = fmaf(w2, v0[j], a[2][j]);
            m[4 + j] = fmaxf(m[4 + j], v1[j]);
            a[0][4 + j] = fmaf(w0, v1[j], a[0][4 + j]);
            a[1][4 + j] = fmaf(w1, v1[j], a[1][4 + j]);
            a[2][4 + j] = fmaf(w2, v1[j], a[2][4 + j]);
        }
    }

    // channel 0 (gap channel) -- loaded AFTER the stream; order is free.
    float xg[8];
    {
        const v4f g0 = *(const v4f*)(xb + lA);
        const v4f g1 = *(const v4f*)(xb + lB);
#pragma unroll
        for (int j = 0; j < 4; ++j) { xg[j] = g0[j]; xg[4 + j] = g1[j]; }
    }

    // add proj (softmax-input init; L2-hot 6KB)
#pragma unroll
    for (int o = 0; o < 3; ++o) {
        const v4f p0 = *(const v4f*)(proj + o * L + lA);
        const v4f p1 = *(const v4f*)(proj + o * L + lB);
#pragma unroll
        for (int j = 0; j < 4; ++j) {
            a[o][j] += p0[j];
            a[o][4 + j] += p1[j];
        }
    }

    float wss[3][8];
#pragma unroll
    for (int o = 0; o < 3; ++o) {
        const v4f s0 = *(const v4f*)(ss_hmm + o * L + lA);
        const v4f s1 = *(const v4f*)(ss_hmm + o * L + lB);
#pragma unroll
        for (int j = 0; j < 4; ++j) { wss[o][j] = s0[j]; wss[o][4 + j] = s1[j]; }
    }

    float lsum = 0.0f, lcnt = 0.0f;
#pragma unroll
    for (int j = 0; j < 8; ++j) {
        if (m[j] > xg[j]) {  // argmax != 0 (first-occurrence tie -> gap)
            const float mm = fmaxf(a[0][j], fmaxf(a[1][j], a[2][j]));
            const float e0 = expf(a[0][j] - mm);
            const float e1 = expf(a[1][j] - mm);
            const float e2 = expf(a[2][j] - mm);
            const float inv = 1.0f / (e0 + e1 + e2);
            lsum = fmaf(wss[0][j] * e0 + wss[1][j] * e1 + wss[2][j] * e2,
                        inv, lsum);
            lcnt += 1.0f;
        }
    }

    // 64-lane wave shuffle reduction; lane 0 stores
#pragma unroll
    for (int off = 32; off >= 1; off >>= 1) {
        lsum += __shfl_down(lsum, off);
        lcnt += __shfl_down(lcnt, off);
    }
    if (t == 0) out[b] = logf(lsum / lcnt);
}

extern "C" void kernel_launch(void* const* d_in, const int* in_sizes, int n_in,
                              void* d_out, int out_size, void* d_ws, size_t ws_size,
                              hipStream_t stream) {
    const float* x       = (const float*)d_in[0];  // [4096,21,512]
    const float* seq_hmm = (const float*)d_in[1];  // [30,512]
    const float* ss_hmm  = (const float*)d_in[2];  // [3,512]
    const float* W       = (const float*)d_in[3];  // [3,50]
    const float* bvec    = (const float*)d_in[4];  // [3]
    float* out = (float*)d_out;                    // [4096]
    float* proj = (float*)d_ws;                    // 3*512 floats = 6 KB

    precompute_proj<<<1, L, 0, stream>>>(seq_hmm, W, bvec, proj);

    const int B = in_sizes[0] / (NCH * L);  // 4096
    qpml_main<<<B, 64, 0, stream>>>(x, ss_hmm, W, proj, out);
}

// Round 5
// 250.033 us; speedup vs baseline: 1.2806x; 1.2806x over previous
//
#include <hip/hip_runtime.h>
#include <math.h>

#define L 512
#define NCH 21      // channels in x
#define H 30        // seq_hmm rows
#define NAA 20      // aa channels used (x[:,1:,:])
#define WSTRIDE 50  // W is [3, 20+H] = [3, 50]

typedef float v4f __attribute__((ext_vector_type(4)));

// proj[o*L + l] = sum_h W[o][20+h] * seq_hmm[h][l] + b[o]
// One-time precompute (R1-proven: cheaper than per-block recompute, R4 -6us).
__global__ void precompute_proj(const float* __restrict__ seq_hmm,
                                const float* __restrict__ W,
                                const float* __restrict__ bvec,
                                float* __restrict__ proj) {
    const int l = threadIdx.x;  // 512 threads, 1 block
    float a0 = bvec[0], a1 = bvec[1], a2 = bvec[2];
#pragma unroll
    for (int h = 0; h < H; ++h) {
        const float s = seq_hmm[h * L + l];
        a0 = fmaf(W[0 * WSTRIDE + NAA + h], s, a0);
        a1 = fmaf(W[1 * WSTRIDE + NAA + h], s, a1);
        a2 = fmaf(W[2 * WSTRIDE + NAA + h], s, a2);
    }
    proj[0 * L + l] = a0;
    proj[1 * L + l] = a1;
    proj[2 * L + l] = a2;
}

// R9: R8's split-contiguous layout, NO VGPR clamp (the one-variable fix).
// Lane t owns cols [4t,4t+4) and [256+4t,4t+260): every dwordx4
// wave-instruction covers a contiguous 1KB half-row (full line payload);
// 40 independent full-width loads/wave/sample.
// VGPR->BW curve measured so far (effective read BW of qpml):
//   VGPR 32 (R5 clamp) -> 0.65 TB/s; VGPR 64 (R8 clamp) -> 1.24 TB/s;
//   unclamped (~160?)  -> 4.0-4.4 TB/s.  In-flight load buffers are THE
// limiter; occupancy moves against it. NEVER add a min-waves clamp.
// NOTE: precise expf/logf required -- __expf/__logf fail absmax (R2: 2.7e-2).
// NOTE: plain cached loads -- nontemporal bypassed L3, +4-10us (R3/R4).
__global__ __launch_bounds__(64) void qpml_main(
        const float* __restrict__ x,       // [B,21,L]
        const float* __restrict__ ss_hmm,  // [3,L]
        const float* __restrict__ W,       // [3,50]
        const float* __restrict__ proj,    // [3,L]
        float* __restrict__ out) {         // [B]
    const int b = blockIdx.x;
    const int t = threadIdx.x;  // 0..63
    const float* xb = x + (size_t)b * NCH * L;
    const int lA = 4 * t;        // first 4-col group
    const int lB = 256 + 4 * t;  // second 4-col group (other half-row)

    // Stream x channels 1..20 with minimal live state: a[3][8] + m[8].
    float a[3][8], m[8];
#pragma unroll
    for (int j = 0; j < 8; ++j) m[j] = -INFINITY;
#pragma unroll
    for (int o = 0; o < 3; ++o)
#pragma unroll
        for (int j = 0; j < 8; ++j) a[o][j] = 0.0f;

#pragma unroll
    for (int c = 1; c < NCH; ++c) {
        const v4f v0 = *(const v4f*)(xb + c * L + lA);
        const v4f v1 = *(const v4f*)(xb + c * L + lB);
        // uniform addresses -> scalar loads, hoisted by compiler
        const float w0 = W[0 * WSTRIDE + (c - 1)];
        const float w1 = W[1 * WSTRIDE + (c - 1)];
        const float w2 = W[2 * WSTRIDE + (c - 1)];
#pragma unroll
        for (int j = 0; j < 4; ++j) {
            m[j] = fmaxf(m[j], v0[j]);
            a[0][j] = fmaf(w0, v0[j], a[0][j]);
            a[1][j] = fmaf(w1, v0[j], a[1][j]);
            a[2][j] = fmaf(w2, v0[j], a[2][j]);
            m[4 + j] = fmaxf(m[4 + j], v1[j]);
            a[0][4 + j] = fmaf(w0, v1[j], a[0][4 + j]);
            a[1][4 + j] = fmaf(w1, v1[j], a[1][4 + j]);
            a[2][4 + j] = fmaf(w2, v1[j], a[2][4 + j]);
        }
    }

    // channel 0 (gap channel) -- loaded after the stream; order is free.
    float xg[8];
    {
        const v4f g0 = *(const v4f*)(xb + lA);
        const v4f g1 = *(const v4f*)(xb + lB);
#pragma unroll
        for (int j = 0; j < 4; ++j) { xg[j] = g0[j]; xg[4 + j] = g1[j]; }
    }

    // add proj (softmax-input init; L2-hot 6KB)
#pragma unroll
    for (int o = 0; o < 3; ++o) {
        const v4f p0 = *(const v4f*)(proj + o * L + lA);
        const v4f p1 = *(const v4f*)(proj + o * L + lB);
#pragma unroll
        for (int j = 0; j < 4; ++j) {
            a[o][j] += p0[j];
            a[o][4 + j] += p1[j];
        }
    }

    float wss[3][8];
#pragma unroll
    for (int o = 0; o < 3; ++o) {
        const v4f s0 = *(const v4f*)(ss_hmm + o * L + lA);
        const v4f s1 = *(const v4f*)(ss_hmm + o * L + lB);
#pragma unroll
        for (int j = 0; j < 4; ++j) { wss[o][j] = s0[j]; wss[o][4 + j] = s1[j]; }
    }

    float lsum = 0.0f, lcnt = 0.0f;
#pragma unroll
    for (int j = 0; j < 8; ++j) {
        if (m[j] > xg[j]) {  // argmax != 0 (first-occurrence tie -> gap)
            const float mm = fmaxf(a[0][j], fmaxf(a[1][j], a[2][j]));
            const float e0 = expf(a[0][j] - mm);
            const float e1 = expf(a[1][j] - mm);
            const float e2 = expf(a[2][j] - mm);
            const float inv = 1.0f / (e0 + e1 + e2);
            lsum = fmaf(wss[0][j] * e0 + wss[1][j] * e1 + wss[2][j] * e2,
                        inv, lsum);
            lcnt += 1.0f;
        }
    }

    // 64-lane wave shuffle reduction; lane 0 stores
#pragma unroll
    for (int off = 32; off >= 1; off >>= 1) {
        lsum += __shfl_down(lsum, off);
        lcnt += __shfl_down(lcnt, off);
    }
    if (t == 0) out[b] = logf(lsum / lcnt);
}

extern "C" void kernel_launch(void* const* d_in, const int* in_sizes, int n_in,
                              void* d_out, int out_size, void* d_ws, size_t ws_size,
                              hipStream_t stream) {
    const float* x       = (const float*)d_in[0];  // [4096,21,512]
    const float* seq_hmm = (const float*)d_in[1];  // [30,512]
    const float* ss_hmm  = (const float*)d_in[2];  // [3,512]
    const float* W       = (const float*)d_in[3];  // [3,50]
    const float* bvec    = (const float*)d_in[4];  // [3]
    float* out = (float*)d_out;                    // [4096]
    float* proj = (float*)d_ws;                    // 3*512 floats = 6 KB

    precompute_proj<<<1, L, 0, stream>>>(seq_hmm, W, bvec, proj);

    const int B = in_sizes[0] / (NCH * L);  // 4096
    qpml_main<<<B, 64, 0, stream>>>(x, ss_hmm, W, proj, out);
}